// Round 12
// baseline (870.732 us; speedup 1.0000x reference)
//
#include <hip/hip_runtime.h>
#include <math.h>

#define ROWS 32
#define NTHREADS 256
#define TAU 2.5e-5f

typedef float f32x4 __attribute__((ext_vector_type(4)));
typedef short s16x8 __attribute__((ext_vector_type(8)));

// d_ws layout (bytes): fragment-ordered bf16-split weights.
// For matrix W[K][N]: tile tl = n16*(K/32) + s covers cols n16*16..+16, k s*32..+32.
// Element [k = s*32 + ks*8 + j][n = n16*16 + lr] stored at (tl*64 + ks*16+lr)*8 + j (shorts)
// -> a wave's B-frag load is ONE coalesced 1KB read: base + lane*16B.
#define WS_WIN_HI (0)
#define WS_WIN_LO (512*1024)
#define WS_W1_HI  (1024*1024)
#define WS_W1_LO  (WS_W1_HI + 128*1024)
#define WS_W2_HI  (WS_W1_HI + 256*1024)
#define WS_W2_LO  (WS_W2_HI + 64*1024)
#define WS_WO_HI  (WS_W2_HI + 128*1024)
#define WS_WO_LO  (WS_WO_HI + 16*1024)

__device__ __forceinline__ unsigned short f2bh(float f) {
    union { float f; unsigned u; } v; v.f = f;
    unsigned r = v.u + 0x7fffu + ((v.u >> 16) & 1u);   // RNE bf16
    return (unsigned short)(r >> 16);
}
__device__ __forceinline__ float bh2f(unsigned short h) {
    union { unsigned u; float f; } v; v.u = ((unsigned)h) << 16;
    return v.f;
}
__device__ __forceinline__ unsigned packsplit(float f) {
    unsigned short h = f2bh(f);
    unsigned short l = f2bh(f - bh2f(h));
    return (unsigned)h | ((unsigned)l << 16);
}

// ---------------- prep: W[k][n] fp32 -> fragment-ordered hi/lo bf16 ----------
__global__ __launch_bounds__(256)
void prep_frag(const float* __restrict__ W_in, const float* __restrict__ W1,
               const float* __restrict__ W2,   const float* __restrict__ Wo,
               void* ws)
{
    const int t    = threadIdx.x;
    const int tg   = blockIdx.x * 4 + (t >> 6);
    const int lane = t & 63;
    const float* src; int N, Kt, tl; size_t offh, offl;
    if (tg < 512)      { src = W_in; N = 256; Kt = 32; tl = tg;       offh = WS_WIN_HI; offl = WS_WIN_LO; }
    else if (tg < 640) { src = W1;   N = 256; Kt = 8;  tl = tg - 512; offh = WS_W1_HI;  offl = WS_W1_LO; }
    else if (tg < 704) { src = W2;   N = 128; Kt = 8;  tl = tg - 640; offh = WS_W2_HI;  offl = WS_W2_LO; }
    else               { src = Wo;   N = 64;  Kt = 4;  tl = tg - 704; offh = WS_WO_HI;  offl = WS_WO_LO; }
    const int n16 = tl / Kt, s = tl % Kt;
    const int lr = lane & 15, ks = lane >> 4;
    const int n  = n16 * 16 + lr;
    const int kb = s * 32 + ks * 8;
    s16x8 hv, lv;
    #pragma unroll
    for (int j = 0; j < 8; ++j) {
        const float f = src[(size_t)(kb + j) * N + n];
        const unsigned short h = f2bh(f);
        hv[j] = (short)h;
        lv[j] = (short)f2bh(f - bh2f(h));
    }
    const size_t base = ((size_t)tl * 64 + lane) * 8;
    *reinterpret_cast<s16x8*>((short*)((char*)ws + offh) + base) = hv;
    *reinterpret_cast<s16x8*>((short*)((char*)ws + offl) + base) = lv;
}

// ---------------- main fused kernel ----------------
struct alignas(16) SMem {
    union {
        unsigned ap[32][260];   // packed (bf16 hi | lo<<16) activations, [row][col]
        struct { double a1d[256]; double h2d[128]; double lgd[64]; } rs;
    } u;
    float  lgt[32][68];
    float2 lnbuf[2][16][2];     // [m-tile][row][n-half] = (sum, sumsq)
    double rred[8];             // rescue LN cross-wave reduce
};

#define MFMA(a, b, c) __builtin_amdgcn_mfma_f32_16x16x32_bf16((a), (b), (c), 0, 0, 0)

// issue all 8 hi/lo B-frag loads of one k-step (coalesced 1KB each)
#define LOADB8(BH, BL, WH, WL, KT, S)                                          \
    _Pragma("unroll")                                                          \
    for (int g = 0; g < 8; ++g) {                                              \
        const size_t tb = (((size_t)(nh * 8 + g) * (KT) + (S)) * 64 + lane) * 8; \
        BH[g] = *reinterpret_cast<const s16x8*>((WH) + tb);                    \
        BL[g] = *reinterpret_cast<const s16x8*>((WL) + tb);                    \
    }

#define LOADB4(BH, BL, WH, WL, KT, S)                                          \
    _Pragma("unroll")                                                          \
    for (int g = 0; g < 4; ++g) {                                              \
        const size_t tb = (((size_t)(nh * 4 + g) * (KT) + (S)) * 64 + lane) * 8; \
        BH[g] = *reinterpret_cast<const s16x8*>((WH) + tb);                    \
        BL[g] = *reinterpret_cast<const s16x8*>((WL) + tb);                    \
    }

#define MFMAG(NG, ACC, AH, AL, BH, BL)                                         \
    _Pragma("unroll")                                                          \
    for (int g = 0; g < (NG); ++g) {                                           \
        ACC[g] = MFMA(AH, BH[g], ACC[g]);                                      \
        ACC[g] = MFMA(AL, BH[g], ACC[g]);                                      \
        ACC[g] = MFMA(AH, BL[g], ACC[g]);                                      \
    }

#define SPLITX(F0, F1, AH, AL) do {                                            \
    const float _xa[8] = {F0.x, F0.y, F0.z, F0.w, F1.x, F1.y, F1.z, F1.w};     \
    _Pragma("unroll")                                                          \
    for (int j = 0; j < 8; ++j) {                                              \
        const unsigned _u = __float_as_uint(_xa[j]);                           \
        AH[j] = (short)(_u >> 16);                                             \
        AL[j] = (short)(__float_as_uint(_xa[j] - __uint_as_float(_u & 0xffff0000u)) >> 16); \
    }                                                                          \
} while (0)

#define UNPACKA(Q0, Q1, AH, AL) do {                                           \
    const unsigned _w[8] = {Q0.x, Q0.y, Q0.z, Q0.w, Q1.x, Q1.y, Q1.z, Q1.w};   \
    _Pragma("unroll")                                                          \
    for (int _j = 0; _j < 8; ++_j) {                                           \
        AH[_j] = (short)(_w[_j] & 0xffff);                                     \
        AL[_j] = (short)(_w[_j] >> 16);                                        \
    }                                                                          \
} while (0)

__global__ __launch_bounds__(NTHREADS, 2)
void gating_mfma(const float* __restrict__ x,
                 const float* __restrict__ W_in, const float* __restrict__ b_in,
                 const float* __restrict__ ln1_g, const float* __restrict__ ln1_b,
                 const float* __restrict__ W1,   const float* __restrict__ b1,
                 const float* __restrict__ ln2_g, const float* __restrict__ ln2_b,
                 const float* __restrict__ W2,   const float* __restrict__ b2,
                 const float* __restrict__ Wo,   const float* __restrict__ bo,
                 const float* __restrict__ temp,
                 const void* __restrict__ ws,
                 float* __restrict__ out)
{
    __shared__ SMem sm;
    __shared__ unsigned cmask;
    const int tid  = threadIdx.x;
    const int lane = tid & 63;
    const int wv   = tid >> 6;        // 0..3
    const int mt   = wv & 1;          // m-tile (rows mt*16..+16)
    const int nh   = wv >> 1;         // n-half
    const int lr   = lane & 15;       // frag row/col
    const int ks   = lane >> 4;       // k-slot (0..3)
    const int row_base = blockIdx.x * ROWS;
    if (tid == 0) cmask = 0;

    float* out_topp = out;
    float* out_topi = out + (size_t)65536 * 8;
    float* out_gp   = out + (size_t)65536 * 16;

    const short* whin_h = (const short*)((const char*)ws + WS_WIN_HI);
    const short* whin_l = (const short*)((const char*)ws + WS_WIN_LO);
    const short* w1_h   = (const short*)((const char*)ws + WS_W1_HI);
    const short* w1_l   = (const short*)((const char*)ws + WS_W1_LO);
    const short* w2_h   = (const short*)((const char*)ws + WS_W2_HI);
    const short* w2_l   = (const short*)((const char*)ws + WS_W2_LO);
    const short* wo_h   = (const short*)((const char*)ws + WS_WO_HI);
    const short* wo_l   = (const short*)((const char*)ws + WS_WO_LO);

    // ================= GEMM1: h0 = relu(x @ W_in + b_in) =================
    // 2-deep register pipeline: issue all 16 B loads of k-step s+1, then
    // sched_barrier, then the 24 MFMAs of k-step s (loads have ~1 region of
    // MFMA+VALU latency cover; 2 waves/SIMD cover the rest).
    f32x4 hacc[8];
    #pragma unroll
    for (int g = 0; g < 8; ++g) hacc[g] = (f32x4)0.f;

    {
        const float* xrow = x + (size_t)(row_base + mt * 16 + lr) * 1024 + ks * 8;
        s16x8 bh0[8], bl0[8], bh1[8], bl1[8];
        s16x8 ah, al;
        float4 xc0 = *reinterpret_cast<const float4*>(xrow);
        float4 xc1 = *reinterpret_cast<const float4*>(xrow + 4);
        LOADB8(bh0, bl0, whin_h, whin_l, 32, 0);
        for (int s = 0; s < 32; s += 2) {
            float4 xd0 = *reinterpret_cast<const float4*>(xrow + (s + 1) * 32);
            float4 xd1 = *reinterpret_cast<const float4*>(xrow + (s + 1) * 32 + 4);
            SPLITX(xc0, xc1, ah, al);
            LOADB8(bh1, bl1, whin_h, whin_l, 32, s + 1);
            __builtin_amdgcn_sched_barrier(0);
            MFMAG(8, hacc, ah, al, bh0, bl0);
            if (s + 2 < 32) {
                xc0 = *reinterpret_cast<const float4*>(xrow + (s + 2) * 32);
                xc1 = *reinterpret_cast<const float4*>(xrow + (s + 2) * 32 + 4);
            }
            SPLITX(xd0, xd1, ah, al);
            if (s + 2 < 32) LOADB8(bh0, bl0, whin_h, whin_l, 32, s + 2);
            __builtin_amdgcn_sched_barrier(0);
            MFMAG(8, hacc, ah, al, bh1, bl1);
        }
    }
    #pragma unroll
    for (int g = 0; g < 8; ++g) {
        const int n = nh * 128 + g * 16 + lr;
        const float bi = b_in[n];
        #pragma unroll
        for (int j = 0; j < 4; ++j) hacc[g][j] = fmaxf(hacc[g][j] + bi, 0.f);
    }

    // ===== LN1 -> relu -> packed a_t =====
    {
        float s4[4] = {0, 0, 0, 0}, q4[4] = {0, 0, 0, 0};
        #pragma unroll
        for (int g = 0; g < 8; ++g)
            #pragma unroll
            for (int j = 0; j < 4; ++j) { s4[j] += hacc[g][j]; q4[j] += hacc[g][j] * hacc[g][j]; }
        #pragma unroll
        for (int m = 1; m < 16; m <<= 1) {
            #pragma unroll
            for (int j = 0; j < 4; ++j) {
                s4[j] += __shfl_xor(s4[j], m);
                q4[j] += __shfl_xor(q4[j], m);
            }
        }
        if (lr == 0) {
            #pragma unroll
            for (int j = 0; j < 4; ++j)
                sm.lnbuf[mt][ks * 4 + j][nh] = make_float2(s4[j], q4[j]);
        }
        __syncthreads();
        float mu[4], rsv[4];
        #pragma unroll
        for (int j = 0; j < 4; ++j) {
            const float2 c0 = sm.lnbuf[mt][ks * 4 + j][0];
            const float2 c1 = sm.lnbuf[mt][ks * 4 + j][1];
            const float ss = c0.x + c1.x, qq = c0.y + c1.y;
            mu[j] = ss * (1.f / 256.f);
            rsv[j] = rsqrtf(qq * (1.f / 256.f) - mu[j] * mu[j] + 1e-5f);
        }
        #pragma unroll
        for (int g = 0; g < 8; ++g) {
            const int n = nh * 128 + g * 16 + lr;
            const float gg = ln1_g[n], bb = ln1_b[n];
            #pragma unroll
            for (int j = 0; j < 4; ++j) {
                const float v = fmaxf((hacc[g][j] - mu[j]) * rsv[j] * gg + bb, 0.f);
                sm.u.ap[mt * 16 + ks * 4 + j][n] = packsplit(v);
            }
        }
    }
    __syncthreads();

    // ================= GEMM2: h1 = a1 @ W1 + b1 + h0 (pipelined) ==========
    {
        f32x4 acc2[8];
        #pragma unroll
        for (int g = 0; g < 8; ++g) acc2[g] = (f32x4)0.f;
        s16x8 bh0[8], bl0[8], bh1[8], bl1[8];
        s16x8 ah, al;
        LOADB8(bh0, bl0, w1_h, w1_l, 8, 0);
        for (int s = 0; s < 8; s += 2) {
            {
                const int kof = s * 32 + ks * 8;
                const uint4 q0 = *reinterpret_cast<const uint4*>(&sm.u.ap[mt * 16 + lr][kof]);
                const uint4 q1 = *reinterpret_cast<const uint4*>(&sm.u.ap[mt * 16 + lr][kof + 4]);
                UNPACKA(q0, q1, ah, al);
            }
            LOADB8(bh1, bl1, w1_h, w1_l, 8, s + 1);
            __builtin_amdgcn_sched_barrier(0);
            MFMAG(8, acc2, ah, al, bh0, bl0);
            {
                const int kof = (s + 1) * 32 + ks * 8;
                const uint4 q0 = *reinterpret_cast<const uint4*>(&sm.u.ap[mt * 16 + lr][kof]);
                const uint4 q1 = *reinterpret_cast<const uint4*>(&sm.u.ap[mt * 16 + lr][kof + 4]);
                UNPACKA(q0, q1, ah, al);
            }
            if (s + 2 < 8) LOADB8(bh0, bl0, w1_h, w1_l, 8, s + 2);
            __builtin_amdgcn_sched_barrier(0);
            MFMAG(8, acc2, ah, al, bh1, bl1);
        }
        #pragma unroll
        for (int g = 0; g < 8; ++g) {
            const int n = nh * 128 + g * 16 + lr;
            const float bv = b1[n];
            #pragma unroll
            for (int j = 0; j < 4; ++j) hacc[g][j] = acc2[g][j] + bv + hacc[g][j];  // hacc := h1
        }
    }
    __syncthreads();   // all a1 reads done before ap rewrite

    // ===== LN2 -> relu -> packed a_t =====
    {
        float s4[4] = {0, 0, 0, 0}, q4[4] = {0, 0, 0, 0};
        #pragma unroll
        for (int g = 0; g < 8; ++g)
            #pragma unroll
            for (int j = 0; j < 4; ++j) { s4[j] += hacc[g][j]; q4[j] += hacc[g][j] * hacc[g][j]; }
        #pragma unroll
        for (int m = 1; m < 16; m <<= 1) {
            #pragma unroll
            for (int j = 0; j < 4; ++j) {
                s4[j] += __shfl_xor(s4[j], m);
                q4[j] += __shfl_xor(q4[j], m);
            }
        }
        if (lr == 0) {
            #pragma unroll
            for (int j = 0; j < 4; ++j)
                sm.lnbuf[mt][ks * 4 + j][nh] = make_float2(s4[j], q4[j]);
        }
        __syncthreads();
        float mu[4], rsv[4];
        #pragma unroll
        for (int j = 0; j < 4; ++j) {
            const float2 c0 = sm.lnbuf[mt][ks * 4 + j][0];
            const float2 c1 = sm.lnbuf[mt][ks * 4 + j][1];
            const float ss = c0.x + c1.x, qq = c0.y + c1.y;
            mu[j] = ss * (1.f / 256.f);
            rsv[j] = rsqrtf(qq * (1.f / 256.f) - mu[j] * mu[j] + 1e-5f);
        }
        #pragma unroll
        for (int g = 0; g < 8; ++g) {
            const int n = nh * 128 + g * 16 + lr;
            const float gg = ln2_g[n], bb = ln2_b[n];
            #pragma unroll
            for (int j = 0; j < 4; ++j) {
                const float v = fmaxf((hacc[g][j] - mu[j]) * rsv[j] * gg + bb, 0.f);
                sm.u.ap[mt * 16 + ks * 4 + j][n] = packsplit(v);
            }
        }
    }
    __syncthreads();

    // ================= GEMM3: h2 = a2 @ W2 + b2 ([32,128], pipelined) ======
    {
        f32x4 acc3[4];
        #pragma unroll
        for (int g = 0; g < 4; ++g) acc3[g] = (f32x4)0.f;
        s16x8 bh0[4], bl0[4], bh1[4], bl1[4];
        s16x8 ah, al;
        LOADB4(bh0, bl0, w2_h, w2_l, 8, 0);
        for (int s = 0; s < 8; s += 2) {
            {
                const int kof = s * 32 + ks * 8;
                const uint4 q0 = *reinterpret_cast<const uint4*>(&sm.u.ap[mt * 16 + lr][kof]);
                const uint4 q1 = *reinterpret_cast<const uint4*>(&sm.u.ap[mt * 16 + lr][kof + 4]);
                UNPACKA(q0, q1, ah, al);
            }
            LOADB4(bh1, bl1, w2_h, w2_l, 8, s + 1);
            __builtin_amdgcn_sched_barrier(0);
            MFMAG(4, acc3, ah, al, bh0, bl0);
            {
                const int kof = (s + 1) * 32 + ks * 8;
                const uint4 q0 = *reinterpret_cast<const uint4*>(&sm.u.ap[mt * 16 + lr][kof]);
                const uint4 q1 = *reinterpret_cast<const uint4*>(&sm.u.ap[mt * 16 + lr][kof + 4]);
                UNPACKA(q0, q1, ah, al);
            }
            if (s + 2 < 8) LOADB4(bh0, bl0, w2_h, w2_l, 8, s + 2);
            __builtin_amdgcn_sched_barrier(0);
            MFMAG(4, acc3, ah, al, bh1, bl1);
        }
        __syncthreads();   // a2 reads done before ap rewrite (h2)
        #pragma unroll
        for (int g = 0; g < 4; ++g) {
            const int n = nh * 64 + g * 16 + lr;
            const float bv = b2[n];
            #pragma unroll
            for (int j = 0; j < 4; ++j)
                sm.u.ap[mt * 16 + ks * 4 + j][n] = packsplit(acc3[g][j] + bv);
        }
    }
    __syncthreads();

    // ================= GEMM4: logits = (h2 @ W_out + b_out)/T =================
    {
        f32x4 acc4[2];
        acc4[0] = (f32x4)0.f; acc4[1] = (f32x4)0.f;
        for (int s = 0; s < 4; ++s) {
            const int kof = s * 32 + ks * 8;
            const uint4 q0 = *reinterpret_cast<const uint4*>(&sm.u.ap[mt * 16 + lr][kof]);
            const uint4 q1 = *reinterpret_cast<const uint4*>(&sm.u.ap[mt * 16 + lr][kof + 4]);
            s16x8 ah, al;
            UNPACKA(q0, q1, ah, al);
            #pragma unroll
            for (int g = 0; g < 2; ++g) {
                const size_t tb = (((size_t)(nh * 2 + g) * 4 + s) * 64 + lane) * 8;
                const s16x8 bh = *reinterpret_cast<const s16x8*>(wo_h + tb);
                const s16x8 bl = *reinterpret_cast<const s16x8*>(wo_l + tb);
                acc4[g] = MFMA(ah, bh, acc4[g]);
                acc4[g] = MFMA(al, bh, acc4[g]);
                acc4[g] = MFMA(ah, bl, acc4[g]);
            }
        }
        const float T = temp[0];
        #pragma unroll
        for (int g = 0; g < 2; ++g) {
            const int n = nh * 32 + g * 16 + lr;
            const float bv = bo[n];
            #pragma unroll
            for (int j = 0; j < 4; ++j)
                sm.lgt[mt * 16 + ks * 4 + j][n] = (acc4[g][j] + bv) / T;
        }
    }
    __syncthreads();

    // ============ softmax + top-8 + contested detection ============
    {
        const float tau = TAU / temp[0];
        for (int j = 0; j < 8; ++j) {
            const int r = wv * 8 + j;
            const float v = sm.lgt[r][lane];
            float m = v;
            #pragma unroll
            for (int mk = 32; mk >= 1; mk >>= 1) m = fmaxf(m, __shfl_xor(m, mk));
            float p = expf(v - m);
            float ssum = p;
            #pragma unroll
            for (int mk = 32; mk >= 1; mk >>= 1) ssum += __shfl_xor(ssum, mk);
            const float gp = p / ssum;
            out_gp[(size_t)(row_base + r) * 64 + lane] = gp;

            float pv = v;
            int   pi = lane;
            float sum8 = 0.f, myv = 0.f, prev = 0.f;
            int   myi = 0;
            bool  contested = false;
            #pragma unroll
            for (int t = 0; t < 9; ++t) {
                float cv = pv;
                int   ci = pi;
                #pragma unroll
                for (int mk = 32; mk >= 1; mk >>= 1) {
                    const float ov = __shfl_xor(cv, mk);
                    const int   oi = __shfl_xor(ci, mk);
                    if (ov > cv || (ov == cv && oi < ci)) { cv = ov; ci = oi; }
                }
                if (t > 0 && (prev - cv) < tau) contested = true;
                prev = cv;
                if (t < 8) {
                    const float g = __shfl(gp, ci);
                    sum8 += g;
                    if (lane == t)  { myv = g; myi = ci; }
                    if (lane == ci) pv = -3.0e38f;
                }
            }
            if (lane < 8) {
                out_topp[(size_t)(row_base + r) * 8 + lane] = myv / sum8;
                out_topi[(size_t)(row_base + r) * 8 + lane] = (float)myi;
            }
            if (lane == 0 && contested) atomicOr(&cmask, 1u << r);
        }
    }

    // ============ fp64 rescue of contested rows (block-parallel) ============
    __syncthreads();
    unsigned cm = cmask;   // uniform across block
    while (cm) {
        const int r = __ffs(cm) - 1;
        cm &= cm - 1;
        const float* xr = x + (size_t)(row_base + r) * 1024;
        const int c = tid;
        const int wvv = tid >> 6;

        double a0 = 0.0, a1 = 0.0, a2 = 0.0, a3 = 0.0;
        for (int k = 0; k < 1024; k += 4) {
            a0 = fma((double)xr[k + 0], (double)W_in[(size_t)(k + 0) * 256 + c], a0);
            a1 = fma((double)xr[k + 1], (double)W_in[(size_t)(k + 1) * 256 + c], a1);
            a2 = fma((double)xr[k + 2], (double)W_in[(size_t)(k + 2) * 256 + c], a2);
            a3 = fma((double)xr[k + 3], (double)W_in[(size_t)(k + 3) * 256 + c], a3);
        }
        const double h0 = fmax((a0 + a1) + (a2 + a3) + (double)b_in[c], 0.0);

        double s = h0, q = h0 * h0;
        #pragma unroll
        for (int m = 1; m < 64; m <<= 1) { s += __shfl_xor(s, m); q += __shfl_xor(q, m); }
        if (lane == 0) { sm.rred[wvv * 2] = s; sm.rred[wvv * 2 + 1] = q; }
        __syncthreads();
        {
            const double ss = (sm.rred[0] + sm.rred[2]) + (sm.rred[4] + sm.rred[6]);
            const double qq = (sm.rred[1] + sm.rred[3]) + (sm.rred[5] + sm.rred[7]);
            const double mu = ss * (1.0 / 256.0);
            const double rsv = 1.0 / sqrt(qq * (1.0 / 256.0) - mu * mu + 1e-5);
            sm.u.rs.a1d[c] = fmax((h0 - mu) * rsv * (double)ln1_g[c] + (double)ln1_b[c], 0.0);
        }
        __syncthreads();

        double b0 = 0.0, b1c = 0.0, b2c = 0.0, b3c = 0.0;
        for (int k = 0; k < 256; k += 4) {
            b0  = fma(sm.u.rs.a1d[k + 0], (double)W1[(size_t)(k + 0) * 256 + c], b0);
            b1c = fma(sm.u.rs.a1d[k + 1], (double)W1[(size_t)(k + 1) * 256 + c], b1c);
            b2c = fma(sm.u.rs.a1d[k + 2], (double)W1[(size_t)(k + 2) * 256 + c], b2c);
            b3c = fma(sm.u.rs.a1d[k + 3], (double)W1[(size_t)(k + 3) * 256 + c], b3c);
        }
        const double h1 = (b0 + b1c) + (b2c + b3c) + (double)b1[c] + h0;

        s = h1; q = h1 * h1;
        #pragma unroll
        for (int m = 1; m < 64; m <<= 1) { s += __shfl_xor(s, m); q += __shfl_xor(q, m); }
        if (lane == 0) { sm.rred[wvv * 2] = s; sm.rred[wvv * 2 + 1] = q; }
        __syncthreads();   // also orders stage-2 a1d reads before rewrite
        {
            const double ss = (sm.rred[0] + sm.rred[2]) + (sm.rred[4] + sm.rred[6]);
            const double qq = (sm.rred[1] + sm.rred[3]) + (sm.rred[5] + sm.rred[7]);
            const double mu = ss * (1.0 / 256.0);
            const double rsv = 1.0 / sqrt(qq * (1.0 / 256.0) - mu * mu + 1e-5);
            sm.u.rs.a1d[c] = fmax((h1 - mu) * rsv * (double)ln2_g[c] + (double)ln2_b[c], 0.0);
        }
        __syncthreads();

        if (c < 128) {
            double d0 = 0.0, d1 = 0.0, d2 = 0.0, d3 = 0.0;
            for (int k = 0; k < 256; k += 4) {
                d0 = fma(sm.u.rs.a1d[k + 0], (double)W2[(size_t)(k + 0) * 128 + c], d0);
                d1 = fma(sm.u.rs.a1d[k + 1], (double)W2[(size_t)(k + 1) * 128 + c], d1);
                d2 = fma(sm.u.rs.a1d[k + 2], (double)W2[(size_t)(k + 2) * 128 + c], d2);
                d3 = fma(sm.u.rs.a1d[k + 3], (double)W2[(size_t)(k + 3) * 128 + c], d3);
            }
            sm.u.rs.h2d[c] = (d0 + d1) + (d2 + d3) + (double)b2[c];
        }
        __syncthreads();

        if (c < 64) {
            double e0 = 0.0, e1 = 0.0;
            for (int k = 0; k < 128; k += 2) {
                e0 = fma(sm.u.rs.h2d[k + 0], (double)Wo[(size_t)(k + 0) * 64 + c], e0);
                e1 = fma(sm.u.rs.h2d[k + 1], (double)Wo[(size_t)(k + 1) * 64 + c], e1);
            }
            sm.u.rs.lgd[c] = (e0 + e1 + (double)bo[c]) / (double)temp[0];
        }
        __syncthreads();

        if (tid < 64) {
            const int ln = tid;
            const double v = sm.u.rs.lgd[ln];
            double m = v;
            #pragma unroll
            for (int mk = 32; mk >= 1; mk >>= 1) m = fmax(m, __shfl_xor(m, mk));
            const double p = exp(v - m);
            double ssum = p;
            #pragma unroll
            for (int mk = 32; mk >= 1; mk >>= 1) ssum += __shfl_xor(ssum, mk);
            const double gp = p / ssum;
            out_gp[(size_t)(row_base + r) * 64 + ln] = (float)gp;

            double pv = gp;
            int    pi = ln;
            double sum8 = 0.0, myv = 0.0;
            int    myi = 0;
            #pragma unroll
            for (int t = 0; t < 8; ++t) {
                double cv = pv;
                int    ci = pi;
                #pragma unroll
                for (int mk = 32; mk >= 1; mk >>= 1) {
                    const double ov = __shfl_xor(cv, mk);
                    const int    oi = __shfl_xor(ci, mk);
                    if (ov > cv || (ov == cv && oi < ci)) { cv = ov; ci = oi; }
                }
                sum8 += cv;
                if (ln == t)  { myv = cv; myi = ci; }
                if (ln == ci) pv = -1.0;
            }
            if (ln < 8) {
                out_topp[(size_t)(row_base + r) * 8 + ln] = (float)(myv / sum8);
                out_topi[(size_t)(row_base + r) * 8 + ln] = (float)myi;
            }
        }
        __syncthreads();
    }
}

extern "C" void kernel_launch(void* const* d_in, const int* in_sizes, int n_in,
                              void* d_out, int out_size, void* d_ws, size_t ws_size,
                              hipStream_t stream) {
    const float* x     = (const float*)d_in[0];
    const float* W_in  = (const float*)d_in[1];
    const float* b_in  = (const float*)d_in[2];
    const float* ln1_g = (const float*)d_in[3];
    const float* ln1_b = (const float*)d_in[4];
    const float* W1    = (const float*)d_in[5];
    const float* b1    = (const float*)d_in[6];
    const float* ln2_g = (const float*)d_in[7];
    const float* ln2_b = (const float*)d_in[8];
    const float* W2    = (const float*)d_in[9];
    const float* b2    = (const float*)d_in[10];
    const float* Wo    = (const float*)d_in[11];
    const float* bo    = (const float*)d_in[12];
    const float* temp  = (const float*)d_in[13];

    prep_frag<<<dim3(180), dim3(256), 0, stream>>>(W_in, W1, W2, Wo, d_ws);
    gating_mfma<<<dim3(65536 / ROWS), dim3(NTHREADS), 0, stream>>>(
        x, W_in, b_in, ln1_g, ln1_b, W1, b1, ln2_g, ln2_b, W2, b2, Wo, bo, temp,
        d_ws, (float*)d_out);
}